// Round 12
// baseline (147.100 us; speedup 1.0000x reference)
//
#include <hip/hip_runtime.h>
#include <math.h>

#define D 128
#define GB 64      // one block per graph (1 block/CU -> LDS budget 160KB)
#define BT 1024    // 16 waves -> 4 waves/SIMD
#define ZP 264     // zsb pitch in bf16 (528 B rows)
#define XLP 74     // xl3 pitch in u16 (148 B rows, odd 4B-stride -> conflict-free col reads)

typedef __attribute__((ext_vector_type(8))) short bf16x8;
typedef __attribute__((ext_vector_type(4))) float f32x4;
typedef __attribute__((ext_vector_type(4))) unsigned u32x4;

__device__ __forceinline__ float leaky01(float v) { return v >= 0.f ? v : 0.01f * v; }
__device__ __forceinline__ unsigned short f2bf(float f) {
    unsigned u = __float_as_uint(f);
    u += 0x7FFFu + ((u >> 16) & 1u);   // RNE (no NaN inputs here)
    return (unsigned short)(u >> 16);
}
__device__ __forceinline__ float bf2f(unsigned short s) {
    return __uint_as_float(((unsigned)s) << 16);
}

// ---- LLC-coherent ops (sc0 sc1 = bypass L1/L2; no cache invalidates/flushes) ----
__device__ __forceinline__ void st_sys_u32(unsigned* p, unsigned v) {
    asm volatile("global_store_dword %0, %1, off sc0 sc1" :: "v"(p), "v"(v) : "memory");
}
__device__ __forceinline__ void st_sys_u128(unsigned* p, u32x4 v) {
    asm volatile("global_store_dwordx4 %0, %1, off sc0 sc1" :: "v"(p), "v"(v) : "memory");
}
__device__ __forceinline__ unsigned ld_sys_u32(const unsigned* p) {
    unsigned v;
    asm volatile("global_load_dword %0, %1, off sc0 sc1\n\ts_waitcnt vmcnt(0)"
                 : "=v"(v) : "v"(p) : "memory");
    return v;
}
__device__ __forceinline__ u32x4 ld_sys_u128(const unsigned* p) {
    u32x4 v;
    asm volatile("global_load_dwordx4 %0, %1, off sc0 sc1\n\ts_waitcnt vmcnt(0)"
                 : "=v"(v) : "v"(p) : "memory");
    return v;
}
__device__ __forceinline__ void waitst() { asm volatile("s_waitcnt vmcnt(0)" ::: "memory"); }

// ---------------- weight pre-convert + flag zero (unchanged r11) ----------------
__global__ void k_wconv(const float* __restrict__ Wm, const float* __restrict__ Wa,
                        const float* __restrict__ Wl,
                        unsigned short* __restrict__ Wmt, unsigned short* __restrict__ Wat,
                        unsigned short* __restrict__ Wlt,
                        unsigned* __restrict__ flags) {
    int gid = blockIdx.x * blockDim.x + threadIdx.x;
    if (blockIdx.x == 0 && threadIdx.x < 8) st_sys_u32(&flags[threadIdx.x], 0u);
    if (gid < 16384) {                       // Wmt[4][128n][128k]
        int o = gid * 4;
        int s = o >> 14, rem = o & 16383, n = rem >> 7, k0 = rem & 127;
        const float* src = Wm + (size_t)s * 16384;
        unsigned short* dst = Wmt + o;
#pragma unroll
        for (int j = 0; j < 4; ++j) dst[j] = f2bf(src[(size_t)(k0 + j) * 128 + n]);
    } else if (gid < 49152) {                // Wat[4][128n][256k]
        int o = (gid - 16384) * 4;
        int s = o >> 15, rem = o & 32767, n = rem >> 8, k0 = rem & 255;
        int row = (k0 < 128) ? k0 : (k0 + 128);
        const float* src = Wa + (size_t)s * 49152;
        unsigned short* dst = Wat + o;
#pragma unroll
        for (int j = 0; j < 4; ++j) dst[j] = f2bf(src[(size_t)(row + j) * 128 + n]);
    } else if (gid < 86016) {                // Wlt[3][384n][128k]
        int o = (gid - 49152) * 4;
        int s = o / 49152, rem = o % 49152, n = rem >> 7, k0 = rem & 127;
        const float* src = Wl + (size_t)s * 49152;
        unsigned short* dst = Wlt + o;
#pragma unroll
        for (int j = 0; j < 4; ++j) dst[j] = f2bf(src[(size_t)(k0 + j) * 384 + n]);
    }
}

// ---------------- fused per-graph kernel ----------------
struct Args {
    const float* x0;
    const int* e_src; const int* e_dst;
    const unsigned short *Wmt, *Wat, *Wlt;
    const float *Wa, *Wr, *bm, *ba, *bl, *br, *att_w, *att_bias;
    unsigned short* xg0;   // [3 steps][64][128] bf16
    unsigned* flagX;       // [3]
    float* out;
};

__global__ __launch_bounds__(BT) void k_mega(Args p) {
    const int tid = threadIdx.x, bid = blockIdx.x, g = bid;
    const int wave = tid >> 6, lane = tid & 63;
    const int m16 = lane & 15, kg = lane >> 4;
    const int wtile = wave >> 1;              // 0..7 -> col tile
    const int half = wave & 1;                // 0/1 -> row-tile pair
    const int col = wtile * 16 + m16;

    __shared__ unsigned short zsb[64][ZP];    // [x | agg] bf16 (33792 B)
    __shared__ unsigned short hs[64][128];    // messages | xg_s swizzled (16384 B)
    __shared__ unsigned short xl3[3][128][XLP];  // all-heads xl, [h][c][s] (56832 B)
    __shared__ float red[3072];               // shared reduction scratch (12 KB)
    __shared__ unsigned mlo[64], mhi[64];
    __shared__ float att_s[3][D];
    __shared__ float xgrow[D];                // own x_att row, persists step->step
    __shared__ float ygmid[D];
    __shared__ float xr3[384];
    __shared__ float alpha3[192];

    unsigned short (*xg_s)[128] = (unsigned short(*)[128])&hs[0][0];  // swizzled overlay

    // ---- adjacency bitmask build (proven r10/r11) ----
    if (tid < 64) { mlo[tid] = 0u; mhi[tid] = 0u; }
    __syncthreads();
    {
        int i0 = g * 1024 + tid;
        int s1 = p.e_src[i0] - g * 64, d1 = p.e_dst[i0] - g * 64;
        atomicOr(s1 < 32 ? &mlo[d1] : &mhi[d1], 1u << (s1 & 31));
    }

    // ---- x lives in registers: 2 row-tiles (mt = half*2 + i) x 4 rows ----
    float xreg[8];
    {
        const float* xp = p.x0 + (size_t)g * 64 * D;
#pragma unroll
        for (int i = 0; i < 2; ++i) {
            int mt = half * 2 + i;
#pragma unroll
            for (int r = 0; r < 4; ++r)
                xreg[i * 4 + r] = xp[(mt * 16 + kg * 4 + r) * D + col];
        }
    }
    __syncthreads();

    for (int step = 0; step < 4; ++step) {
        // ---- stage x -> zsb[:,0:128) ----
#pragma unroll
        for (int i = 0; i < 2; ++i) {
            int mt = half * 2 + i;
#pragma unroll
            for (int r = 0; r < 4; ++r) zsb[mt * 16 + kg * 4 + r][col] = f2bf(xreg[i * 4 + r]);
        }
        if (step < 3 && tid < 384) att_s[tid >> 7][tid & 127] = p.att_w[step * 384 + tid];
        __syncthreads();

        // ---- message GEMM: h = leaky(x @ Wm + bm) ----
        {
            const unsigned short* Wb = p.Wmt + ((size_t)(step * 128 + col) * 128 + kg * 8);
            bf16x8 bB[4];
#pragma unroll
            for (int kt = 0; kt < 4; ++kt) bB[kt] = *(const bf16x8*)(Wb + kt * 32);
            float bb = p.bm[step * 128 + col];
#pragma unroll
            for (int i = 0; i < 2; ++i) {
                int mt = half * 2 + i;
                f32x4 acc = {0.f, 0.f, 0.f, 0.f};
#pragma unroll
                for (int kt = 0; kt < 4; ++kt) {
                    bf16x8 a = *(const bf16x8*)&zsb[mt * 16 + m16][kt * 32 + kg * 8];
                    acc = __builtin_amdgcn_mfma_f32_16x16x32_bf16(a, bB[kt], acc, 0, 0, 0);
                }
#pragma unroll
                for (int r = 0; r < 4; ++r)
                    hs[mt * 16 + kg * 4 + r][col] = f2bf(leaky01(acc[r] + bb));
            }
        }
        __syncthreads();

        // ---- seg-max via bitmasks: 4 rows per wave ----
        {
            int r0 = wave * 4;
            unsigned lo[4], hi[4];
#pragma unroll
            for (int r = 0; r < 4; ++r) {
                lo[r] = (unsigned)__builtin_amdgcn_readfirstlane((int)mlo[r0 + r]);
                hi[r] = (unsigned)__builtin_amdgcn_readfirstlane((int)mhi[r0 + r]);
            }
            float m0[4], m1[4];
#pragma unroll
            for (int r = 0; r < 4; ++r) { m0[r] = -INFINITY; m1[r] = -INFINITY; }
#pragma unroll 4
            for (int s = 0; s < 32; ++s) {
                unsigned hv = *(const unsigned*)&hs[s][lane * 2];
                float v0 = bf2f((unsigned short)(hv & 0xffffu));
                float v1 = bf2f((unsigned short)(hv >> 16));
#pragma unroll
                for (int r = 0; r < 4; ++r)
                    if ((lo[r] >> s) & 1u) { m0[r] = fmaxf(m0[r], v0); m1[r] = fmaxf(m1[r], v1); }
            }
#pragma unroll 4
            for (int s = 32; s < 64; ++s) {
                unsigned hv = *(const unsigned*)&hs[s][lane * 2];
                float v0 = bf2f((unsigned short)(hv & 0xffffu));
                float v1 = bf2f((unsigned short)(hv >> 16));
#pragma unroll
                for (int r = 0; r < 4; ++r)
                    if ((hi[r] >> (s - 32)) & 1u) { m0[r] = fmaxf(m0[r], v0); m1[r] = fmaxf(m1[r], v1); }
            }
#pragma unroll
            for (int r = 0; r < 4; ++r) {
                unsigned pk = (lo[r] | hi[r])
                                  ? (((unsigned)f2bf(m1[r]) << 16) | (unsigned)f2bf(m0[r]))
                                  : 0u;
                *(unsigned*)&zsb[r0 + r][128 + lane * 2] = pk;
            }
        }

        // ---- ygmid = xgrow @ Wa[128:256,:] (exact f32; 8 chunks of 16 k) ----
        if (step > 0) {
            int n = tid & 127, q = tid >> 7;   // q 0..7
            float a = 0.f;
            const float* Wmid = p.Wa + (size_t)step * 49152 + (size_t)(128 + q * 16) * 128 + n;
#pragma unroll 8
            for (int k2 = 0; k2 < 16; ++k2) a += xgrow[q * 16 + k2] * Wmid[(size_t)k2 * 128];
            red[q * 128 + n] = a;
            __syncthreads();
            if (tid < 128) {
                float s8 = 0.f;
#pragma unroll
                for (int q2 = 0; q2 < 8; ++q2) s8 += red[q2 * 128 + tid];
                ygmid[tid] = s8;
            }
        }
        __syncthreads();   // covers seg-max writes (and ygmid)

        // ---- update GEMM K=256: x' = leaky([x|agg]@Wat + ygmid + ba) + x ----
        {
            const unsigned short* Wb = p.Wat + ((size_t)(step * 128 + col) * 256 + kg * 8);
            bf16x8 bB[8];
#pragma unroll
            for (int kt = 0; kt < 8; ++kt) bB[kt] = *(const bf16x8*)(Wb + kt * 32);
            float extra = p.ba[step * 128 + col] + (step > 0 ? ygmid[col] : 0.f);
#pragma unroll
            for (int i = 0; i < 2; ++i) {
                int mt = half * 2 + i;
                f32x4 acc = {0.f, 0.f, 0.f, 0.f};
#pragma unroll
                for (int kt = 0; kt < 8; ++kt) {
                    bf16x8 a = *(const bf16x8*)&zsb[mt * 16 + m16][kt * 32 + kg * 8];
                    acc = __builtin_amdgcn_mfma_f32_16x16x32_bf16(a, bB[kt], acc, 0, 0, 0);
                }
#pragma unroll
                for (int r = 0; r < 4; ++r) {
                    float v = leaky01(acc[r] + extra) + xreg[i * 4 + r];
                    xreg[i * 4 + r] = v;
                    if (step == 3) p.out[((size_t)g * 64 + mt * 16 + kg * 4 + r) * D + col] = v;
                }
            }
        }

        // ---- GAT: each block computes its OWN x_att row g, all heads flat ----
        if (step < 3) {
            __syncthreads();   // update reads of zsb/hs done before xg_s overlay
            unsigned short* xg0g = p.xg0 + (size_t)step * 8192;
            if (bid == 0) {    // publish graph0 x
#pragma unroll
                for (int i = 0; i < 2; ++i) {
                    int mt = half * 2 + i;
#pragma unroll
                    for (int r = 0; r < 4; ++r) {
                        int row = mt * 16 + kg * 4 + r;
                        unsigned off = (unsigned)(row * 256 + col * 2) ^ (unsigned)((row & 7) << 4);
                        *(unsigned short*)((char*)&xg_s[0][0] + off) = f2bf(xreg[i * 4 + r]);
                    }
                }
                __syncthreads();
                {
                    unsigned boff = (unsigned)tid * 16;
                    int row = tid >> 4;
                    u32x4 v = *(u32x4*)((char*)&xg_s[0][0] + (boff ^ (unsigned)((row & 7) << 4)));
                    st_sys_u128((unsigned*)((char*)xg0g + boff), v);
                }
                waitst();
                __syncthreads();
                if (tid == 0) st_sys_u32(p.flagX + step, 1u);
            } else {
                if (tid == 0) {
                    int it = 0;
                    while (ld_sys_u32(p.flagX + step) == 0 && it++ < (1 << 22))
                        __builtin_amdgcn_s_sleep(2);
                }
                __syncthreads();
                {
                    unsigned boff = (unsigned)tid * 16;
                    int row = tid >> 4;
                    u32x4 v = ld_sys_u128((const unsigned*)((const char*)xg0g + boff));
                    *(u32x4*)((char*)&xg_s[0][0] + (boff ^ (unsigned)((row & 7) << 4))) = v;
                }
                __syncthreads();
            }

            // -- phase G1: xl for ALL heads (MFMA) + xr partials (f32 matvec) --
            for (int h = 0; h < 3; ++h) {
                const unsigned short* Wb = p.Wlt + ((size_t)(step * 384 + h * 128 + col) * 128 + kg * 8);
                bf16x8 bB[4];
#pragma unroll
                for (int kt = 0; kt < 4; ++kt) bB[kt] = *(const bf16x8*)(Wb + kt * 32);
                float bb = p.bl[step * 384 + h * 128 + col];
#pragma unroll
                for (int i = 0; i < 2; ++i) {
                    int mt = half * 2 + i;
                    f32x4 acc = {0.f, 0.f, 0.f, 0.f};
#pragma unroll
                    for (int kt = 0; kt < 4; ++kt) {
                        int row = mt * 16 + m16;
                        unsigned off = (unsigned)(row * 256 + (kt * 32 + kg * 8) * 2) ^ (unsigned)((row & 7) << 4);
                        bf16x8 a = *(const bf16x8*)((const char*)&xg_s[0][0] + off);
                        acc = __builtin_amdgcn_mfma_f32_16x16x32_bf16(a, bB[kt], acc, 0, 0, 0);
                    }
                    int s0 = mt * 16 + kg * 4;
                    unsigned pk0 = (unsigned)f2bf(acc[0] + bb) | ((unsigned)f2bf(acc[1] + bb) << 16);
                    unsigned pk1 = (unsigned)f2bf(acc[2] + bb) | ((unsigned)f2bf(acc[3] + bb) << 16);
                    *(unsigned*)&xl3[h][col][s0] = pk0;
                    *(unsigned*)&xl3[h][col][s0 + 2] = pk1;
                }
            }
            if (tid < 768) {   // xr partials: 2 chunks of 64 k, all 3 heads
                int q = (tid >= 384) ? 1 : 0;
                int n3 = tid - q * 384;
                int h = n3 >> 7, n = n3 & 127;
                float a = 0.f;
                const float* Wrp = p.Wr + (size_t)step * 49152 + (size_t)(q * 64) * 384 + h * 128 + n;
#pragma unroll 8
                for (int k2 = 0; k2 < 64; ++k2) {
                    int k = q * 64 + k2;
                    unsigned b = ((unsigned)(g * 256 + k * 2)) ^ (unsigned)((g & 7) << 4);
                    float xv = bf2f(*(const unsigned short*)((const char*)&xg_s[0][0] + b));
                    a += xv * Wrp[(size_t)k2 * 384];
                }
                red[q * 384 + n3] = a;
            }
            __syncthreads();
            if (tid < 384) xr3[tid] = red[tid] + red[384 + tid] + p.br[step * 384 + tid];
            __syncthreads();

            // -- phase G2: logits, all heads (lane = src, k split across 16 waves) --
            {
                int kb = wave * 8;
#pragma unroll
                for (int h = 0; h < 3; ++h) {
                    float part = 0.f;
#pragma unroll
                    for (int kk = 0; kk < 8; ++kk) {
                        int k = kb + kk;
                        float t = bf2f(xl3[h][k][lane]) + xr3[h * 128 + k];
                        t = (t >= 0.f) ? t : 0.2f * t;
                        part += att_s[h][k] * t;
                    }
                    red[(h * 16 + wave) * 64 + lane] = part;
                }
            }
            __syncthreads();
            if (tid < 192) {   // softmax per head (wave = head)
                int h = tid >> 6;
                float lg = 0.f;
#pragma unroll
                for (int w2 = 0; w2 < 16; ++w2) lg += red[(h * 16 + w2) * 64 + lane];
                float mx = lg;
#pragma unroll
                for (int o = 32; o > 0; o >>= 1) mx = fmaxf(mx, __shfl_xor(mx, o));
                float a = __expf(lg - mx), sm = a;
#pragma unroll
                for (int o = 32; o > 0; o >>= 1) sm += __shfl_xor(sm, o);
                alpha3[h * 64 + lane] = a / sm;
            }
            __syncthreads();

            // -- phase G3: PV all heads (6 chunks: h x half-src) --
            {
                int c = tid & 127, q = tid >> 7;
                if (q < 6) {
                    int h = q >> 1, sq = q & 1;
                    float pv = 0.f;
#pragma unroll
                    for (int s2 = 0; s2 < 32; ++s2) {
                        int s = sq * 32 + s2;
                        pv += alpha3[h * 64 + s] * bf2f(xl3[h][c][s]);
                    }
                    red[q * 128 + c] = pv;
                }
            }
            __syncthreads();
            if (tid < 128) {
                float accO = red[tid] + red[128 + tid] + red[256 + tid]
                           + red[384 + tid] + red[512 + tid] + red[640 + tid];
                xgrow[tid] = leaky01(accO * (1.f / 3.f) + p.att_bias[step * 128 + tid]);
            }
        }
        __syncthreads();   // end-of-step: zsb/hs safe to overwrite; xgrow visible
    }
}

extern "C" void kernel_launch(void* const* d_in, const int* in_sizes, int n_in,
                              void* d_out, int out_size, void* d_ws, size_t ws_size,
                              hipStream_t stream) {
    (void)n_in; (void)out_size; (void)ws_size;
    const float* x_in     = (const float*)d_in[0];
    const int*   edge_idx = (const int*)d_in[1];
    // d_in[2] batch_ind, d_in[3] edge_complete: structurally determined -> unused
    const float* Wm  = (const float*)d_in[4];
    const float* bm  = (const float*)d_in[5];
    const float* Wa  = (const float*)d_in[6];
    const float* ba  = (const float*)d_in[7];
    const float* Wl  = (const float*)d_in[8];
    const float* bl  = (const float*)d_in[9];
    const float* Wr  = (const float*)d_in[10];
    const float* br  = (const float*)d_in[11];
    const float* att_w    = (const float*)d_in[12];
    const float* att_bias = (const float*)d_in[13];
    const int E = in_sizes[1] / 2;

    char* ws = (char*)d_ws;
    size_t off = 0;
    auto alloc = [&](size_t bytes) { void* pp = ws + off; off += (bytes + 255) & ~size_t(255); return pp; };
    unsigned short* xg0 = (unsigned short*)alloc((size_t)3 * 64 * 128 * 2);
    unsigned short* Wmt = (unsigned short*)alloc((size_t)4 * 128 * 128 * 2);
    unsigned short* Wat = (unsigned short*)alloc((size_t)4 * 128 * 256 * 2);
    unsigned short* Wlt = (unsigned short*)alloc((size_t)3 * 384 * 128 * 2);
    unsigned* flags     = (unsigned*)alloc(8 * 4);

    k_wconv<<<336, 256, 0, stream>>>(Wm, Wa, Wl, Wmt, Wat, Wlt, flags);

    Args a;
    a.x0 = x_in;
    a.e_src = edge_idx;
    a.e_dst = edge_idx + E;
    a.Wmt = Wmt; a.Wat = Wat; a.Wlt = Wlt;
    a.Wa = Wa; a.Wr = Wr; a.bm = bm; a.ba = ba; a.bl = bl; a.br = br;
    a.att_w = att_w; a.att_bias = att_bias;
    a.xg0 = xg0; a.flagX = flags;
    a.out = (float*)d_out;
    void* kargs[] = { (void*)&a };
    (void)hipLaunchCooperativeKernel((void*)k_mega, dim3(GB), dim3(BT), kargs, 0, stream);
}

// Round 13
// 122.981 us; speedup vs baseline: 1.1961x; 1.1961x over previous
//
#include <hip/hip_runtime.h>
#include <math.h>

#define D 128
#define GB 64      // one block per graph
#define BT 1024    // 16 waves -> 4 waves/SIMD
#define ZP 264     // zsb pitch in bf16 (528 B rows)
#define XLP 74     // xl3 pitch in u16 (148 B rows)

typedef __attribute__((ext_vector_type(8))) short bf16x8;
typedef __attribute__((ext_vector_type(4))) float f32x4;
typedef __attribute__((ext_vector_type(4))) unsigned u32x4;

__device__ __forceinline__ float leaky01(float v) { return v >= 0.f ? v : 0.01f * v; }
__device__ __forceinline__ unsigned short f2bf(float f) {
    unsigned u = __float_as_uint(f);
    u += 0x7FFFu + ((u >> 16) & 1u);   // RNE (no NaN inputs here)
    return (unsigned short)(u >> 16);
}
__device__ __forceinline__ float bf2f(unsigned short s) {
    return __uint_as_float(((unsigned)s) << 16);
}

// ---- LLC-coherent ops (sc0 sc1 = bypass L1/L2) ----
__device__ __forceinline__ void st_sys_u32(unsigned* p, unsigned v) {
    asm volatile("global_store_dword %0, %1, off sc0 sc1" :: "v"(p), "v"(v) : "memory");
}
__device__ __forceinline__ void st_sys_u128(unsigned* p, u32x4 v) {
    asm volatile("global_store_dwordx4 %0, %1, off sc0 sc1" :: "v"(p), "v"(v) : "memory");
}
__device__ __forceinline__ unsigned ld_sys_u32(const unsigned* p) {
    unsigned v;
    asm volatile("global_load_dword %0, %1, off sc0 sc1\n\ts_waitcnt vmcnt(0)"
                 : "=v"(v) : "v"(p) : "memory");
    return v;
}
__device__ __forceinline__ u32x4 ld_sys_u128(const unsigned* p) {
    u32x4 v;
    asm volatile("global_load_dwordx4 %0, %1, off sc0 sc1\n\ts_waitcnt vmcnt(0)"
                 : "=v"(v) : "v"(p) : "memory");
    return v;
}
__device__ __forceinline__ void waitst() { asm volatile("s_waitcnt vmcnt(0)" ::: "memory"); }

// ---------------- weight pre-convert + flag zero (unchanged r12) ----------------
__global__ void k_wconv(const float* __restrict__ Wm, const float* __restrict__ Wa,
                        const float* __restrict__ Wl,
                        unsigned short* __restrict__ Wmt, unsigned short* __restrict__ Wat,
                        unsigned short* __restrict__ Wlt,
                        unsigned* __restrict__ flags) {
    int gid = blockIdx.x * blockDim.x + threadIdx.x;
    if (blockIdx.x == 0 && threadIdx.x < 8) st_sys_u32(&flags[threadIdx.x], 0u);
    if (gid < 16384) {                       // Wmt[4][128n][128k]
        int o = gid * 4;
        int s = o >> 14, rem = o & 16383, n = rem >> 7, k0 = rem & 127;
        const float* src = Wm + (size_t)s * 16384;
        unsigned short* dst = Wmt + o;
#pragma unroll
        for (int j = 0; j < 4; ++j) dst[j] = f2bf(src[(size_t)(k0 + j) * 128 + n]);
    } else if (gid < 49152) {                // Wat[4][128n][256k]
        int o = (gid - 16384) * 4;
        int s = o >> 15, rem = o & 32767, n = rem >> 8, k0 = rem & 255;
        int row = (k0 < 128) ? k0 : (k0 + 128);
        const float* src = Wa + (size_t)s * 49152;
        unsigned short* dst = Wat + o;
#pragma unroll
        for (int j = 0; j < 4; ++j) dst[j] = f2bf(src[(size_t)(row + j) * 128 + n]);
    } else if (gid < 86016) {                // Wlt[3][384n][128k]
        int o = (gid - 49152) * 4;
        int s = o / 49152, rem = o % 49152, n = rem >> 7, k0 = rem & 127;
        const float* src = Wl + (size_t)s * 49152;
        unsigned short* dst = Wlt + o;
#pragma unroll
        for (int j = 0; j < 4; ++j) dst[j] = f2bf(src[(size_t)(k0 + j) * 384 + n]);
    }
}

// ---------------- fused per-graph kernel ----------------
struct Args {
    const float* x0;
    const int* e_src; const int* e_dst;
    const unsigned short *Wmt, *Wat, *Wlt;
    const float *Wa, *Wr, *bm, *ba, *bl, *br, *att_w, *att_bias;
    unsigned short* xg0;   // [3 steps][64][128] bf16
    unsigned* flagX;       // [3]
    float* out;
};

__global__ __launch_bounds__(BT) void k_mega(Args p) {
    const int tid = threadIdx.x, bid = blockIdx.x, g = bid;
    const int wave = tid >> 6, lane = tid & 63;
    const int m16 = lane & 15, kg = lane >> 4;
    const int wtile = wave >> 1;
    const int half = wave & 1;
    const int col = wtile * 16 + m16;

    __shared__ unsigned short zsb[64][ZP];       // [x | agg] bf16 (33792 B)
    __shared__ unsigned short hs[64][128];       // messages | xg_s swizzled
    __shared__ unsigned short xl3[3][128][XLP];  // all-heads xl (56832 B)
    __shared__ float red[4608];                  // [0,1024) ygmid | [0,3072) G2 | [3072,3840) xr | [3840,4608) PV
    __shared__ unsigned mlo[64], mhi[64];
    __shared__ float att_s[3][D];
    __shared__ float br_s[384];
    __shared__ float xgrow[D];

    unsigned short (*xg_s)[128] = (unsigned short(*)[128])&hs[0][0];

    // ---- adjacency bitmask build (proven) ----
    if (tid < 64) { mlo[tid] = 0u; mhi[tid] = 0u; }
    __syncthreads();
    {
        int i0 = g * 1024 + tid;
        int s1 = p.e_src[i0] - g * 64, d1 = p.e_dst[i0] - g * 64;
        atomicOr(s1 < 32 ? &mlo[d1] : &mhi[d1], 1u << (s1 & 31));
    }

    // ---- x in registers: 2 row-tiles x 4 rows ----
    float xreg[8];
    {
        const float* xp = p.x0 + (size_t)g * 64 * D;
#pragma unroll
        for (int i = 0; i < 2; ++i) {
            int mt = half * 2 + i;
#pragma unroll
            for (int r = 0; r < 4; ++r)
                xreg[i * 4 + r] = xp[(mt * 16 + kg * 4 + r) * D + col];
        }
    }
    __syncthreads();

    for (int step = 0; step < 4; ++step) {
        // ==== P0: final-combine (prev GAT) + stage x + att/br loads ====
        if (step > 0 && tid < 128) {
            float accO = red[3840 + tid] + red[3840 + 128 + tid] + red[3840 + 256 + tid]
                       + red[3840 + 384 + tid] + red[3840 + 512 + tid] + red[3840 + 640 + tid];
            xgrow[tid] = leaky01(accO * (1.f / 3.f) + p.att_bias[(step - 1) * 128 + tid]);
        }
#pragma unroll
        for (int i = 0; i < 2; ++i) {
            int mt = half * 2 + i;
#pragma unroll
            for (int r = 0; r < 4; ++r) zsb[mt * 16 + kg * 4 + r][col] = f2bf(xreg[i * 4 + r]);
        }
        if (step < 3 && tid < 384) {
            att_s[tid >> 7][tid & 127] = p.att_w[step * 384 + tid];
            br_s[tid] = p.br[step * 384 + tid];
        }
        __syncthreads();   // B1

        // ==== P1: message GEMM ====
        {
            const unsigned short* Wb = p.Wmt + ((size_t)(step * 128 + col) * 128 + kg * 8);
            bf16x8 bB[4];
#pragma unroll
            for (int kt = 0; kt < 4; ++kt) bB[kt] = *(const bf16x8*)(Wb + kt * 32);
            float bb = p.bm[step * 128 + col];
#pragma unroll
            for (int i = 0; i < 2; ++i) {
                int mt = half * 2 + i;
                f32x4 acc = {0.f, 0.f, 0.f, 0.f};
#pragma unroll
                for (int kt = 0; kt < 4; ++kt) {
                    bf16x8 a = *(const bf16x8*)&zsb[mt * 16 + m16][kt * 32 + kg * 8];
                    acc = __builtin_amdgcn_mfma_f32_16x16x32_bf16(a, bB[kt], acc, 0, 0, 0);
                }
#pragma unroll
                for (int r = 0; r < 4; ++r)
                    hs[mt * 16 + kg * 4 + r][col] = f2bf(leaky01(acc[r] + bb));
            }
        }
        __syncthreads();   // B2

        // ==== P2: Wat prefetch + ygmid partials + sparse seg-max ====
        bf16x8 wat[8];
        {
            const unsigned short* WbU = p.Wat + ((size_t)(step * 128 + col) * 256 + kg * 8);
#pragma unroll
            for (int kt = 0; kt < 8; ++kt) wat[kt] = *(const bf16x8*)(WbU + kt * 32);
        }
        if (step > 0) {
            int n = tid & 127, q = tid >> 7;
            float a = 0.f;
            const float* Wmid = p.Wa + (size_t)step * 49152 + (size_t)(128 + q * 16) * 128 + n;
#pragma unroll 8
            for (int k2 = 0; k2 < 16; ++k2) a += xgrow[q * 16 + k2] * Wmid[(size_t)k2 * 128];
            red[q * 128 + n] = a;
        }
        {
            int r0 = wave * 4;
#pragma unroll
            for (int r = 0; r < 4; ++r) {
                int row = r0 + r;
                unsigned lo = (unsigned)__builtin_amdgcn_readfirstlane((int)mlo[row]);
                unsigned hi = (unsigned)__builtin_amdgcn_readfirstlane((int)mhi[row]);
                unsigned long long mk = (((unsigned long long)hi) << 32) | lo;
                float m0 = -INFINITY, m1 = -INFINITY;
                unsigned long long t = mk;
                while (t) {
                    int s = __builtin_ctzll(t);
                    t &= t - 1;
                    unsigned hv = *(const unsigned*)&hs[s][lane * 2];
                    m0 = fmaxf(m0, bf2f((unsigned short)(hv & 0xffffu)));
                    m1 = fmaxf(m1, bf2f((unsigned short)(hv >> 16)));
                }
                unsigned pk = mk ? (((unsigned)f2bf(m1) << 16) | (unsigned)f2bf(m0)) : 0u;
                *(unsigned*)&zsb[row][128 + lane * 2] = pk;
            }
        }
        __syncthreads();   // B3

        // ==== P3: update GEMM (ygmid inlined); block0 fills xg_s ====
        {
            float yg = 0.f;
            if (step > 0) {
#pragma unroll
                for (int q2 = 0; q2 < 8; ++q2) yg += red[q2 * 128 + col];
            }
            float extra = p.ba[step * 128 + col] + yg;
#pragma unroll
            for (int i = 0; i < 2; ++i) {
                int mt = half * 2 + i;
                f32x4 acc = {0.f, 0.f, 0.f, 0.f};
#pragma unroll
                for (int kt = 0; kt < 8; ++kt) {
                    bf16x8 a = *(const bf16x8*)&zsb[mt * 16 + m16][kt * 32 + kg * 8];
                    acc = __builtin_amdgcn_mfma_f32_16x16x32_bf16(a, wat[kt], acc, 0, 0, 0);
                }
#pragma unroll
                for (int r = 0; r < 4; ++r) {
                    float v = leaky01(acc[r] + extra) + xreg[i * 4 + r];
                    xreg[i * 4 + r] = v;
                    if (step == 3) p.out[((size_t)g * 64 + mt * 16 + kg * 4 + r) * D + col] = v;
                }
            }
            if (bid == 0 && step < 3) {
#pragma unroll
                for (int i = 0; i < 2; ++i) {
                    int mt = half * 2 + i;
#pragma unroll
                    for (int r = 0; r < 4; ++r) {
                        int row = mt * 16 + kg * 4 + r;
                        unsigned off = (unsigned)(row * 256 + col * 2) ^ (unsigned)((row & 7) << 4);
                        *(unsigned short*)((char*)&xg_s[0][0] + off) = f2bf(xreg[i * 4 + r]);
                    }
                }
            }
        }
        __syncthreads();   // B4

        if (step < 3) {
            unsigned short* xg0g = p.xg0 + (size_t)step * 8192;
            // ==== P4/P5: one LLC hop ====
            if (bid == 0) {
                {
                    unsigned boff = (unsigned)tid * 16;
                    int row = tid >> 4;
                    u32x4 v = *(u32x4*)((char*)&xg_s[0][0] + (boff ^ (unsigned)((row & 7) << 4)));
                    st_sys_u128((unsigned*)((char*)xg0g + boff), v);
                }
                waitst();
                __syncthreads();   // B5
                if (tid == 0) st_sys_u32(p.flagX + step, 1u);
                __syncthreads();   // B6
            } else {
                if (tid == 0) {
                    int it = 0;
                    while (ld_sys_u32(p.flagX + step) == 0 && it++ < (1 << 22))
                        __builtin_amdgcn_s_sleep(2);
                }
                __syncthreads();   // B5
                {
                    unsigned boff = (unsigned)tid * 16;
                    int row = tid >> 4;
                    u32x4 v = ld_sys_u128((const unsigned*)((const char*)xg0g + boff));
                    *(u32x4*)((char*)&xg_s[0][0] + (boff ^ (unsigned)((row & 7) << 4))) = v;
                }
                __syncthreads();   // B6
            }

            // ==== P6 (G1): xl all heads (MFMA) + xr partials ====
            for (int h = 0; h < 3; ++h) {
                const unsigned short* Wb = p.Wlt + ((size_t)(step * 384 + h * 128 + col) * 128 + kg * 8);
                bf16x8 bB[4];
#pragma unroll
                for (int kt = 0; kt < 4; ++kt) bB[kt] = *(const bf16x8*)(Wb + kt * 32);
                float bb = p.bl[step * 384 + h * 128 + col];
#pragma unroll
                for (int i = 0; i < 2; ++i) {
                    int mt = half * 2 + i;
                    f32x4 acc = {0.f, 0.f, 0.f, 0.f};
#pragma unroll
                    for (int kt = 0; kt < 4; ++kt) {
                        int row = mt * 16 + m16;
                        unsigned off = (unsigned)(row * 256 + (kt * 32 + kg * 8) * 2) ^ (unsigned)((row & 7) << 4);
                        bf16x8 a = *(const bf16x8*)((const char*)&xg_s[0][0] + off);
                        acc = __builtin_amdgcn_mfma_f32_16x16x32_bf16(a, bB[kt], acc, 0, 0, 0);
                    }
                    int s0 = mt * 16 + kg * 4;
                    unsigned pk0 = (unsigned)f2bf(acc[0] + bb) | ((unsigned)f2bf(acc[1] + bb) << 16);
                    unsigned pk1 = (unsigned)f2bf(acc[2] + bb) | ((unsigned)f2bf(acc[3] + bb) << 16);
                    *(unsigned*)&xl3[h][col][s0] = pk0;
                    *(unsigned*)&xl3[h][col][s0 + 2] = pk1;
                }
            }
            if (tid < 768) {   // xr partials: 2 chunks of 64 k, 3 heads
                int q = (tid >= 384) ? 1 : 0;
                int n3 = tid - q * 384;
                int h = n3 >> 7, n = n3 & 127;
                float a = 0.f;
                const float* Wrp = p.Wr + (size_t)step * 49152 + (size_t)(q * 64) * 384 + h * 128 + n;
#pragma unroll 8
                for (int k2 = 0; k2 < 64; ++k2) {
                    int k = q * 64 + k2;
                    unsigned b = ((unsigned)(g * 256 + k * 2)) ^ (unsigned)((g & 7) << 4);
                    float xv = bf2f(*(const unsigned short*)((const char*)&xg_s[0][0] + b));
                    a += xv * Wrp[(size_t)k2 * 384];
                }
                red[3072 + q * 384 + n3] = a;
            }
            __syncthreads();   // B7

            // ==== P7 (G2): logit partials (xr inlined) ====
            {
                int kb = wave * 8;
#pragma unroll
                for (int h = 0; h < 3; ++h) {
                    float part = 0.f;
#pragma unroll
                    for (int kk = 0; kk < 8; ++kk) {
                        int k = kb + kk;
                        float xr = red[3072 + h * 128 + k] + red[3072 + 384 + h * 128 + k]
                                 + br_s[h * 128 + k];
                        float t = bf2f(xl3[h][k][lane]) + xr;
                        t = (t >= 0.f) ? t : 0.2f * t;
                        part += att_s[h][k] * t;
                    }
                    red[(h * 16 + wave) * 64 + lane] = part;
                }
            }
            __syncthreads();   // B8

            // ==== P8: softmax (wave-redundant) + PV partials ====
            {
                int q = tid >> 7, c = tid & 127;
                if (q < 6) {
                    int h = q >> 1, sq = q & 1;
                    float lg = 0.f;
#pragma unroll
                    for (int w2 = 0; w2 < 16; ++w2) lg += red[(h * 16 + w2) * 64 + lane];
                    float mx = lg;
#pragma unroll
                    for (int o = 32; o > 0; o >>= 1) mx = fmaxf(mx, __shfl_xor(mx, o));
                    float a = __expf(lg - mx), sm = a;
#pragma unroll
                    for (int o = 32; o > 0; o >>= 1) sm += __shfl_xor(sm, o);
                    float alpha = a / sm;
                    float pv = 0.f;
#pragma unroll
                    for (int s2 = 0; s2 < 32; ++s2) {
                        int s = sq * 32 + s2;
                        float as = __shfl(alpha, s);
                        pv += as * bf2f(xl3[h][c][s]);
                    }
                    red[3840 + q * 128 + c] = pv;
                }
            }
            __syncthreads();   // B9
        }
    }
}

extern "C" void kernel_launch(void* const* d_in, const int* in_sizes, int n_in,
                              void* d_out, int out_size, void* d_ws, size_t ws_size,
                              hipStream_t stream) {
    (void)n_in; (void)out_size; (void)ws_size;
    const float* x_in     = (const float*)d_in[0];
    const int*   edge_idx = (const int*)d_in[1];
    // d_in[2] batch_ind, d_in[3] edge_complete: structurally determined -> unused
    const float* Wm  = (const float*)d_in[4];
    const float* bm  = (const float*)d_in[5];
    const float* Wa  = (const float*)d_in[6];
    const float* ba  = (const float*)d_in[7];
    const float* Wl  = (const float*)d_in[8];
    const float* bl  = (const float*)d_in[9];
    const float* Wr  = (const float*)d_in[10];
    const float* br  = (const float*)d_in[11];
    const float* att_w    = (const float*)d_in[12];
    const float* att_bias = (const float*)d_in[13];
    const int E = in_sizes[1] / 2;

    char* ws = (char*)d_ws;
    size_t off = 0;
    auto alloc = [&](size_t bytes) { void* pp = ws + off; off += (bytes + 255) & ~size_t(255); return pp; };
    unsigned short* xg0 = (unsigned short*)alloc((size_t)3 * 64 * 128 * 2);
    unsigned short* Wmt = (unsigned short*)alloc((size_t)4 * 128 * 128 * 2);
    unsigned short* Wat = (unsigned short*)alloc((size_t)4 * 128 * 256 * 2);
    unsigned short* Wlt = (unsigned short*)alloc((size_t)3 * 384 * 128 * 2);
    unsigned* flags     = (unsigned*)alloc(8 * 4);

    k_wconv<<<336, 256, 0, stream>>>(Wm, Wa, Wl, Wmt, Wat, Wlt, flags);

    Args a;
    a.x0 = x_in;
    a.e_src = edge_idx;
    a.e_dst = edge_idx + E;
    a.Wmt = Wmt; a.Wat = Wat; a.Wlt = Wlt;
    a.Wa = Wa; a.Wr = Wr; a.bm = bm; a.ba = ba; a.bl = bl; a.br = br;
    a.att_w = att_w; a.att_bias = att_bias;
    a.xg0 = xg0; a.flagX = flags;
    a.out = (float*)d_out;
    void* kargs[] = { (void*)&a };
    (void)hipLaunchCooperativeKernel((void*)k_mega, dim3(GB), dim3(BT), kargs, 0, stream);
}